// Round 12
// baseline (59.731 us; speedup 1.0000x reference)
//
#include <hip/hip_runtime.h>

#define HOP     256
#define WD      32
#define NFRM    4096
#define TLEN    1048832        // FRAMELEN + HOP*(NFRM-1)
#define LROW    786688         // 448 + 4095*192
#define FPB     8              // frames per block (1 wave = 16 chains)
#define XSTR    484            // x floats per frame (121 quads)
#define DSTR    420            // g floats per chain (105 quads)
#define XQn     121
#define DQn     105
#define XTOT    (FPB*XSTR + 16)     // 3888
#define GTOT    (16*DSTR + 16)      // 6736

// 4-lane (quad) butterfly sum; result in all 4 lanes of each quad. 2 levels.
__device__ __forceinline__ float red4(float v) {
    v += __int_as_float(__builtin_amdgcn_update_dpp(0, __float_as_int(v), 0xB1, 0xF, 0xF, true)); // quad_perm[1,0,3,2]
    v += __int_as_float(__builtin_amdgcn_update_dpp(0, __float_as_int(v), 0x4E, 0xF, 0xF, true)); // quad_perm[2,3,0,1]
    return v;
}

#define CL(v) __builtin_amdgcn_fmed3f((v), -65535.0f, 65535.0f)

// One LMS step: 16 taps/lane. GV = 0.05*d. gm = fmaf(-0.05,s,GV) = 0.05*e.
// SO += IND*s ; EO += IND*gm  (lane c captures sub-step r==c).
#define STEPX(GV, IND, SO, EO, \
    X0,X1,X2,X3,X4,X5,X6,X7,X8,X9,Xa,Xb,Xc,Xd,Xe,Xf) do {            \
    float pA = w0*(X0);  pA = fmaf(w1,(X1),pA);                       \
    pA = fmaf(w2,(X2),pA);  pA = fmaf(w3,(X3),pA);                    \
    float pB = w4*(X4);  pB = fmaf(w5,(X5),pB);                       \
    pB = fmaf(w6,(X6),pB);  pB = fmaf(w7,(X7),pB);                    \
    float pC = w8*(X8);  pC = fmaf(w9,(X9),pC);                       \
    pC = fmaf(wa,(Xa),pC);  pC = fmaf(wb,(Xb),pC);                    \
    float pD = wc*(Xc);  pD = fmaf(wd,(Xd),pD);                       \
    pD = fmaf(we,(Xe),pD);  pD = fmaf(wf,(Xf),pD);                    \
    float p  = (pA + pB) + (pC + pD);                                 \
    float s  = red4(p);                                               \
    SO = fmaf((IND), s, SO);                                          \
    float gm = fmaf(-0.05f, s, (GV));                                 \
    EO = fmaf((IND), gm, EO);                                         \
    w0 = CL(fmaf(gm,(X0),w0));  w1 = CL(fmaf(gm,(X1),w1));            \
    w2 = CL(fmaf(gm,(X2),w2));  w3 = CL(fmaf(gm,(X3),w3));            \
    w4 = CL(fmaf(gm,(X4),w4));  w5 = CL(fmaf(gm,(X5),w5));            \
    w6 = CL(fmaf(gm,(X6),w6));  w7 = CL(fmaf(gm,(X7),w7));            \
    w8 = CL(fmaf(gm,(X8),w8));  w9 = CL(fmaf(gm,(X9),w9));            \
    wa = CL(fmaf(gm,(Xa),wa));  wb = CL(fmaf(gm,(Xb),wb));            \
    wc = CL(fmaf(gm,(Xc),wc));  wd = CL(fmaf(gm,(Xd),wd));            \
    we = CL(fmaf(gm,(Xe),we));  wf = CL(fmaf(gm,(Xf),wf));            \
} while (0)

// 4 steps from the 5-quad window Q0..Q4 and gv quad G4.
#define PHASE(Q0,Q1,Q2,Q3,Q4, G4, SO, EO) do {                        \
    STEPX(G4.x, i0, SO, EO, Q0.x,Q0.y,Q0.z,Q0.w, Q1.x,Q1.y,Q1.z,Q1.w,\
          Q2.x,Q2.y,Q2.z,Q2.w, Q3.x,Q3.y,Q3.z,Q3.w);                  \
    STEPX(G4.y, i1, SO, EO, Q0.y,Q0.z,Q0.w,Q1.x, Q1.y,Q1.z,Q1.w,Q2.x,\
          Q2.y,Q2.z,Q2.w,Q3.x, Q3.y,Q3.z,Q3.w,Q4.x);                  \
    STEPX(G4.z, i2, SO, EO, Q0.z,Q0.w,Q1.x,Q1.y, Q1.z,Q1.w,Q2.x,Q2.y,\
          Q2.z,Q2.w,Q3.x,Q3.y, Q3.z,Q3.w,Q4.x,Q4.y);                  \
    STEPX(G4.w, i3, SO, EO, Q0.w,Q1.x,Q1.y,Q1.z, Q1.w,Q2.x,Q2.y,Q2.z,\
          Q2.w,Q3.x,Q3.y,Q3.z, Q3.w,Q4.x,Q4.y,Q4.z);                  \
} while (0)

// block = 64 threads = 1 wave = 16 chains (L=4: one quad per chain).
// 512 blocks; ~half the SIMDs idle BY DESIGN — the 2-level DPP chain is
// short enough that a single wave is nearly issue-bound.
__global__ void __launch_bounds__(64, 2)
lms_kernel(const float* __restrict__ dmat, const float* __restrict__ xvec,
           float* __restrict__ out)
{
    __shared__ __align__(16) float lx[XTOT];
    __shared__ __align__(16) float lg[GTOT];   // 0.05 * d, per chain slot

    const int tid = threadIdx.x;
    const int f0  = blockIdx.x * FPB;

    // ---- stage: 968 x-quads + 1680 g-quads ----
    for (int i = tid; i < 968 + 1680; i += 64) {
        if (i < 968) {
            int fr = i / XQn, k = i - fr * XQn;
            ((float4*)lx)[fr * XQn + k] =
                *(const float4*)(xvec + (size_t)(f0 + fr) * HOP + 4 * k);
        } else {
            int j2 = i - 968;
            int ch = j2 / DQn, k = j2 - ch * DQn;   // ch = (r<<1)|b
            int b = ch & 1, r = ch >> 1;
            float4 v = *(const float4*)(dmat + (size_t)b * TLEN
                                        + (size_t)(f0 + r) * HOP + WD + 4 * k);
            float4 g2;
            g2.x = 0.05f * v.x; g2.y = 0.05f * v.y;
            g2.z = 0.05f * v.z; g2.w = 0.05f * v.w;
            ((float4*)lg)[ch * DQn + k] = g2;
        }
    }
    __syncthreads();

    const int ch = tid >> 2;               // chain 0..15
    const int c  = tid & 3;                // lane within quad: taps 16c..16c+15
    const int fl = ch >> 1;                // local frame 0..7
    const int b  = ch & 1;                 // batch
    const int f  = f0 + fl;                // global frame
    const bool early = (f == 0);

    // per-lane quad pointers (both 16B aligned)
    const float4* __restrict__ xq = (const float4*)(lx + fl * XSTR + 16 * c);
    const float4* __restrict__ gq = (const float4*)(lg + ch * DSTR);

    float* od = out + (size_t)b * LROW + 32 + (size_t)192 * f;
    float* oe = od + 2 * (size_t)LROW;

    // leading 32 zeros of the 4 output rows
    if (blockIdx.x == 0) {
        int pos = tid & 31;
        for (int r2 = tid >> 5; r2 < 4; r2 += 2)
            out[(size_t)r2 * LROW + pos] = 0.0f;
    }

    // sub-step capture indicators
    const float i0 = (c == 0) ? 1.f : 0.f, i1 = (c == 1) ? 1.f : 0.f;
    const float i2 = (c == 2) ? 1.f : 0.f, i3 = (c == 3) ? 1.f : 0.f;

    float w0=0.f,w1=0.f,w2=0.f,w3=0.f,w4=0.f,w5=0.f,w6=0.f,w7=0.f,
          w8=0.f,w9=0.f,wa=0.f,wb=0.f,wc=0.f,wd=0.f,we=0.f,wf=0.f;

    // prologue: 8-quad x window (group j uses relative quads 4j..4j+7)
    float4 W0 = xq[0], W1 = xq[1], W2 = xq[2], W3 = xq[3],
           W4 = xq[4], W5 = xq[5], W6 = xq[6], W7 = xq[7];

    #pragma unroll 1
    for (int j = 0; j < 26; ++j) {
        float4 Ga = gq[4*j],   Gb = gq[4*j+1],
               Gc = gq[4*j+2], Gd = gq[4*j+3];
        float4 N0 = xq[4*j+8],  N1 = xq[4*j+9],
               N2 = xq[4*j+10], N3 = xq[4*j+11];

        float so0=0.f,so1=0.f,so2=0.f,so3=0.f;
        float eo0=0.f,eo1=0.f,eo2=0.f,eo3=0.f;

        PHASE(W0,W1,W2,W3,W4, Ga, so0, eo0);
        PHASE(W1,W2,W3,W4,W5, Gb, so1, eo1);
        PHASE(W2,W3,W4,W5,W6, Gc, so2, eo2);
        PHASE(W3,W4,W5,W6,W7, Gd, so3, eo3);

        if (j >= 14 || early) {
            od[16*j +  0 + c] = so0;  oe[16*j +  0 + c] = 20.0f * eo0;
            od[16*j +  4 + c] = so1;  oe[16*j +  4 + c] = 20.0f * eo1;
            od[16*j +  8 + c] = so2;  oe[16*j +  8 + c] = 20.0f * eo2;
            od[16*j + 12 + c] = so3;  oe[16*j + 12 + c] = 20.0f * eo3;
        }

        W0 = W4; W1 = W5; W2 = W6; W3 = W7;
        W4 = N0; W5 = N1; W6 = N2; W7 = N3;
    }
}

extern "C" void kernel_launch(void* const* d_in, const int* in_sizes, int n_in,
                              void* d_out, int out_size, void* d_ws, size_t ws_size,
                              hipStream_t stream) {
    const float* dmat = (const float*)d_in[0];   // (2, TLEN)
    const float* xvec = (const float*)d_in[1];   // (TLEN,)
    float* out = (float*)d_out;                  // [d_est(2,LROW), e(2,LROW)]

    hipLaunchKernelGGL(lms_kernel, dim3(NFRM / FPB), dim3(64), 0, stream,
                       dmat, xvec, out);
}

// Round 13
// 49.111 us; speedup vs baseline: 1.2163x; 1.2163x over previous
//
#include <hip/hip_runtime.h>

#define HOP     256
#define WD      32
#define NFRM    4096
#define TLEN    1048832        // FRAMELEN + HOP*(NFRM-1)
#define LROW    786688         // 448 + 4095*192
#define XSTR    484            // x floats per frame (121 quads; 484 % 32 == 4)
#define DSTR    420            // g floats per chain (105 quads; 420 % 32 == 4)
#define XQn     121
#define DQn     105
#define XTOT    (2*XSTR + 40)  // guard for dead prefetch overrun
#define GTOT    (4*DSTR + 8)

// 8-lane xor-butterfly sum within each aligned 8-lane group; result in all 8.
// Only 3 dependent cross-lane hops (vs 4 for 16 lanes) — chain-shortening.
__device__ __forceinline__ float red8(float v) {
    v += __int_as_float(__builtin_amdgcn_update_dpp(0, __float_as_int(v), 0xB1,  0xF, 0xF, true)); // quad_perm xor1
    v += __int_as_float(__builtin_amdgcn_update_dpp(0, __float_as_int(v), 0x4E,  0xF, 0xF, true)); // quad_perm xor2
    v += __int_as_float(__builtin_amdgcn_update_dpp(0, __float_as_int(v), 0x141, 0xF, 0xF, true)); // row_half_mirror
    return v;
}

#define CL(v) __builtin_amdgcn_fmed3f((v), -65535.0f, 65535.0f)

// One LMS step: 8 taps/lane. GV = 0.05*d. gm = fmaf(-0.05,s,GV) = 0.05*e.
// Capture (off critical path): so += IND*s ; eo += IND*gm.
#define STEP8(X0,X1,X2,X3,X4,X5,X6,X7, GV, IND) do {              \
    float pA = w0 * (X0);                                         \
    pA = fmaf(w1, (X1), pA);                                      \
    pA = fmaf(w2, (X2), pA);                                      \
    pA = fmaf(w3, (X3), pA);                                      \
    float pB = w4 * (X4);                                         \
    pB = fmaf(w5, (X5), pB);                                      \
    pB = fmaf(w6, (X6), pB);                                      \
    pB = fmaf(w7, (X7), pB);                                      \
    float s  = red8(pA + pB);                                     \
    float gm = fmaf(-0.05f, s, (GV));                             \
    so = fmaf((IND), s,  so);                                     \
    eo = fmaf((IND), gm, eo);                                     \
    w0 = CL(fmaf(gm, (X0), w0));                                  \
    w1 = CL(fmaf(gm, (X1), w1));                                  \
    w2 = CL(fmaf(gm, (X2), w2));                                  \
    w3 = CL(fmaf(gm, (X3), w3));                                  \
    w4 = CL(fmaf(gm, (X4), w4));                                  \
    w5 = CL(fmaf(gm, (X5), w5));                                  \
    w6 = CL(fmaf(gm, (X6), w6));                                  \
    w7 = CL(fmaf(gm, (X7), w7));                                  \
} while (0)

// 8 steps (one store-group) from 4 x-quads + 2 gv-quads.
#define GROUP8(q0,q1,q2,q3, da,db) do {                           \
    STEP8(q0.x,q0.y,q0.z,q0.w,q1.x,q1.y,q1.z,q1.w, da.x, i0);     \
    STEP8(q0.y,q0.z,q0.w,q1.x,q1.y,q1.z,q1.w,q2.x, da.y, i1);     \
    STEP8(q0.z,q0.w,q1.x,q1.y,q1.z,q1.w,q2.x,q2.y, da.z, i2);     \
    STEP8(q0.w,q1.x,q1.y,q1.z,q1.w,q2.x,q2.y,q2.z, da.w, i3);     \
    STEP8(q1.x,q1.y,q1.z,q1.w,q2.x,q2.y,q2.z,q2.w, db.x, i4);     \
    STEP8(q1.y,q1.z,q1.w,q2.x,q2.y,q2.z,q2.w,q3.x, db.y, i5);     \
    STEP8(q1.z,q1.w,q2.x,q2.y,q2.z,q2.w,q3.x,q3.y, db.z, i6);     \
    STEP8(q1.w,q2.x,q2.y,q2.z,q2.w,q3.x,q3.y,q3.z, db.w, i7);     \
} while (0)

// block = 64 threads = 1 wave = 4 chains on lanes 0..31 (L=8, 8 taps/lane).
// Lanes 32..63 duplicate-compute (stores masked): idle lanes are free since
// wave64 issue cost is per-wave — but the reduce tree is 3 hops, not 4.
// 2048 blocks -> 2 waves/SIMD, mutual stall covering.
__global__ void __launch_bounds__(64, 2)
lms_kernel(const float* __restrict__ dmat, const float* __restrict__ xvec,
           float* __restrict__ out)
{
    __shared__ __align__(16) float lx[XTOT];
    __shared__ __align__(16) float lg[GTOT];   // 0.05 * d, per chain

    const int tid = threadIdx.x;
    const int f0  = blockIdx.x * 2;

    // ---- stage: 242 x-quads + 420 g-quads (all 64 lanes help) ----
    for (int i = tid; i < 242 + 420; i += 64) {
        if (i < 242) {
            int fr = (i >= XQn) ? 1 : 0;
            int k  = i - fr * XQn;
            ((float4*)lx)[i] =
                *(const float4*)(xvec + (size_t)(f0 + fr) * HOP + 4 * k);
        } else {
            int j   = i - 242;
            int idx = j / DQn, k = j - idx * DQn;   // idx = b*2 + r
            int b = idx >> 1, r = idx & 1;
            float4 v = *(const float4*)(dmat + (size_t)b * TLEN
                                        + (size_t)(f0 + r) * HOP + WD + 4 * k);
            float4 g2;
            g2.x = 0.05f * v.x; g2.y = 0.05f * v.y;
            g2.z = 0.05f * v.z; g2.w = 0.05f * v.w;
            ((float4*)lg)[j] = g2;
        }
    }
    __syncthreads();

    const int lane = tid & 63;
    const int row  = (lane >> 3) & 3;      // chain 0..3 (lanes>=32 duplicate)
    const int col  = lane & 7;             // taps 8*col .. 8*col+7
    const int fl   = row >> 1;             // local frame 0..1
    const int b    = row & 1;              // batch
    const int f    = f0 + fl;              // global frame
    const bool early = (f == 0);
    const bool wr  = (lane < 32);          // store mask
    const int ci   = b * 2 + fl;           // chain slot in lg

    const float4* __restrict__ xq = (const float4*)(lx + fl * XSTR + 8 * col);
    const float4* __restrict__ gq = (const float4*)(lg + ci * DSTR);

    float* od = out + (size_t)b * LROW + 32 + (size_t)192 * f;
    float* oe = od + 2 * (size_t)LROW;

    // leading 32 zeros of the 4 output rows
    if (blockIdx.x == 0) {
        int pos = tid & 31;
        for (int r2 = tid >> 5; r2 < 4; r2 += 2)
            out[(size_t)r2 * LROW + pos] = 0.0f;
    }

    // per-lane step indicators (1.0 in the lane that captures sub-step k)
    const float i0 = (col == 0) ? 1.f : 0.f, i1 = (col == 1) ? 1.f : 0.f;
    const float i2 = (col == 2) ? 1.f : 0.f, i3 = (col == 3) ? 1.f : 0.f;
    const float i4 = (col == 4) ? 1.f : 0.f, i5 = (col == 5) ? 1.f : 0.f;
    const float i6 = (col == 6) ? 1.f : 0.f, i7 = (col == 7) ? 1.f : 0.f;

    float w0 = 0.f, w1 = 0.f, w2 = 0.f, w3 = 0.f,
          w4 = 0.f, w5 = 0.f, w6 = 0.f, w7 = 0.f;

    // prologue: group 0 window into A
    float4 ax0 = xq[0], ax1 = xq[1], ax2 = xq[2], ax3 = xq[3];
    float4 ad0 = gq[0], ad1 = gq[1];

    for (int i = 0; i < 26; ++i) {
        // prefetch group 2i+1 into B (covered by the 8 A-steps)
        float4 bx0 = xq[4*i+2], bx1 = xq[4*i+3],
               bx2 = xq[4*i+4], bx3 = xq[4*i+5];
        float4 bd0 = gq[4*i+2], bd1 = gq[4*i+3];
        {
            float so = 0.f, eo = 0.f;
            GROUP8(ax0, ax1, ax2, ax3, ad0, ad1);
            int g = 2 * i;
            if ((g >= 28 || early) && wr) {
                od[8*g + col] = so;
                oe[8*g + col] = 20.0f * eo;
            }
        }
        // prefetch group 2i+2 into A (dead-guarded reads at i==25)
        ax0 = xq[4*i+4]; ax1 = xq[4*i+5]; ax2 = xq[4*i+6]; ax3 = xq[4*i+7];
        ad0 = gq[4*i+4]; ad1 = gq[4*i+5];
        {
            float so = 0.f, eo = 0.f;
            GROUP8(bx0, bx1, bx2, bx3, bd0, bd1);
            int g = 2 * i + 1;
            if ((g >= 28 || early) && wr) {
                od[8*g + col] = so;
                oe[8*g + col] = 20.0f * eo;
            }
        }
    }
}

extern "C" void kernel_launch(void* const* d_in, const int* in_sizes, int n_in,
                              void* d_out, int out_size, void* d_ws, size_t ws_size,
                              hipStream_t stream) {
    const float* dmat = (const float*)d_in[0];   // (2, TLEN)
    const float* xvec = (const float*)d_in[1];   // (TLEN,)
    float* out = (float*)d_out;                  // [d_est(2,LROW), e(2,LROW)]

    hipLaunchKernelGGL(lms_kernel, dim3(NFRM / 2), dim3(64), 0, stream,
                       dmat, xvec, out);
}